// Round 6
// baseline (2502.148 us; speedup 1.0000x reference)
//
#include <hip/hip_runtime.h>
#include <hip/hip_cooperative_groups.h>

namespace cg = cooperative_groups;

typedef __bf16 bf16_t;
typedef __bf16 bf16x8 __attribute__((ext_vector_type(8)));
typedef __bf16 bf16x4 __attribute__((ext_vector_type(4)));
typedef float  f32x4  __attribute__((ext_vector_type(4)));
typedef int    i32x4  __attribute__((ext_vector_type(4)));

#define PL 136   // padded row stride (elems) for [t][128] bf16 tiles
#define PX 264   // padded row stride (elems) for [t][256] bf16 tiles
#define SMB 52224

__device__ __forceinline__ f32x4 mfma16(bf16x8 a, bf16x8 b, f32x4 c) {
    return __builtin_amdgcn_mfma_f32_16x16x32_bf16(a, b, c, 0, 0, 0);
}

// ---------------- weight conversion to MFMA fragment order ----------------
__global__ void conv_batch(const float* __restrict__ src, bf16_t* __restrict__ dst,
                           int M, int K, int cnt) {
    int idx = blockIdx.x * 256 + threadIdx.x;
    int MK = M * K;
    if (idx >= MK * cnt) return;
    int lay = idx / MK;
    int r = idx - lay * MK;
    int j = r & 7, lane = (r >> 3) & 63, rest = r >> 9;
    int KB = K >> 5;
    int kb = rest % KB, mt = rest / KB;
    int m = mt * 16 + (lane & 15);
    int k = kb * 32 + ((lane >> 4) << 3) + j;
    dst[idx] = (bf16_t)src[(size_t)lay * MK + m * K + k];
}

__global__ void conv_dil(const float* __restrict__ dw, bf16_t* __restrict__ dst) {
    int idx = blockIdx.x * 256 + threadIdx.x;   // 30*65536 total
    int lay = idx >> 16, r = idx & 65535;
    int j = r & 7, lane = (r >> 3) & 63, rest = r >> 9;
    int kb = rest & 7, mt = rest >> 3;
    int m = mt * 16 + (lane & 15);
    int k = kb * 32 + ((lane >> 4) << 3) + j;
    float v = (k < 128) ? dw[(((size_t)lay * 256 + m) * 128 + k) * 2]
                        : dw[(((size_t)lay * 256 + m) * 128 + (k - 128)) * 2 + 1];
    dst[idx] = (bf16_t)v;
}

__global__ void cond_kernel(const float* __restrict__ cond_w,
                            const float* __restrict__ end2_w,
                            const float* __restrict__ end2_b,
                            const float* __restrict__ en,
                            float* __restrict__ cond_all,
                            float* __restrict__ cond2) {
    __shared__ f32x4 en_s[1024];
    int bi = blockIdx.x;
    int i = bi >> 2, n = bi & 3, o = threadIdx.x;
    const f32x4* ep = (const f32x4*)(en + (size_t)n * 4096);
    for (int idx = threadIdx.x; idx < 1024; idx += 256) en_s[idx] = ep[idx];
    __syncthreads();
    const float* W = (i < 30) ? cond_w + ((size_t)i * 256 + o) * 256
                              : end2_w + (size_t)o * 256;
    f32x4 a0 = {0.f,0.f,0.f,0.f}, a1 = a0, a2 = a0, a3 = a0;
    for (int c = 0; c < 256; c += 4) {
        f32x4 wv = *(const f32x4*)(W + c);
        #pragma unroll
        for (int cc = 0; cc < 4; ++cc) {
            float wf = wv[cc];
            a0 += wf * en_s[(c + cc) * 4 + 0];
            a1 += wf * en_s[(c + cc) * 4 + 1];
            a2 += wf * en_s[(c + cc) * 4 + 2];
            a3 += wf * en_s[(c + cc) * 4 + 3];
        }
    }
    float bias = (i < 30) ? 0.f : end2_b[o];
    float* dst = (i < 30) ? cond_all + (((size_t)i * 4 + n) * 256 + o) * 16
                          : cond2 + ((size_t)n * 256 + o) * 16;
    f32x4* d4 = (f32x4*)dst;
    d4[0] = a0 + bias; d4[1] = a1 + bias; d4[2] = a2 + bias; d4[3] = a3 + bias;
}

__global__ void setup_a(int* __restrict__ a_tab) {
    if (threadIdx.x == 0 && blockIdx.x == 0) {
        a_tab[29] = 4096;
        for (int i = 28; i >= 0; --i) {
            int nx = a_tab[i + 1] - (1 << ((i + 1) % 10));
            a_tab[i] = nx < 4096 ? (nx & ~63) : 4096;
        }
    }
}

// ================= stage bodies (shared by persistent + fallback) =================

// u in [0,508): n = u&3, t0 = 64 + (u>>2)*64
__device__ __forceinline__ void body_start(
    int u, int tid, const float* __restrict__ x, bf16_t* __restrict__ la,
    float* __restrict__ sbuf, const bf16_t* __restrict__ A1,
    const bf16_t* __restrict__ A2, char* smem)
{
    bf16_t* xt = (bf16_t*)smem;               // stride PX, 33792 B
    bf16_t* l0 = (bf16_t*)(smem + 34816);     // stride PL, 17408 B
    int n = u & 3, t0 = 64 + (u >> 2) * 64;
    int lane = tid & 63, w = tid >> 6, i16 = lane & 15, q = lane >> 4;
    f32x4 z = {0.f,0.f,0.f,0.f};
    {
        int t = tid & 63;
        for (int c = tid >> 6; c < 256; c += 8)
            xt[t * PX + c] = (bf16_t)x[((size_t)n * 256 + c) * 8192 + t0 + t];
    }
    __syncthreads();
    f32x4 acc[4] = {z,z,z,z};
    #pragma unroll
    for (int kb = 0; kb < 8; ++kb) {
        int koff = kb * 32 + q * 8;
        bf16x8 bf[4];
        #pragma unroll
        for (int nt = 0; nt < 4; ++nt)
            bf[nt] = *(const bf16x8*)(xt + (nt * 16 + i16) * PX + koff);
        bf16x8 af = *(const bf16x8*)(A1 + (((size_t)w * 8 + kb) * 64 + lane) * 8);
        #pragma unroll
        for (int nt = 0; nt < 4; ++nt) acc[nt] = mfma16(af, bf[nt], acc[nt]);
    }
    #pragma unroll
    for (int nt = 0; nt < 4; ++nt)
        #pragma unroll
        for (int j = 0; j < 4; ++j)
            l0[(nt * 16 + i16) * PL + w * 16 + q * 4 + j] = (bf16_t)acc[nt][j];
    __syncthreads();
    {
        int r = tid >> 4, col = (tid & 15) * 8;
        #pragma unroll
        for (int p = 0; p < 2; ++p) {
            int rr = r + p * 32;
            *(i32x4*)(la + ((size_t)n * 8192 + t0 + rr) * 128 + col) =
                *(const i32x4*)(l0 + rr * PL + col);
        }
    }
    if (t0 >= 4096) {
        f32x4 a2[2][4] = {{z,z,z,z},{z,z,z,z}};
        #pragma unroll
        for (int kb = 0; kb < 4; ++kb) {
            int koff = kb * 32 + q * 8;
            bf16x8 bf[4];
            #pragma unroll
            for (int nt = 0; nt < 4; ++nt)
                bf[nt] = *(const bf16x8*)(l0 + (nt * 16 + i16) * PL + koff);
            #pragma unroll
            for (int mt2 = 0; mt2 < 2; ++mt2) {
                bf16x8 af = *(const bf16x8*)(A2 + ((((size_t)2 * w + mt2) * 4 + kb) * 64 + lane) * 8);
                #pragma unroll
                for (int nt = 0; nt < 4; ++nt) a2[mt2][nt] = mfma16(af, bf[nt], a2[mt2][nt]);
            }
        }
        float* sp = sbuf + (size_t)n * 256 * 4096 + (t0 - 4096);
        #pragma unroll
        for (int mt2 = 0; mt2 < 2; ++mt2)
            #pragma unroll
            for (int nt = 0; nt < 4; ++nt)
                #pragma unroll
                for (int j = 0; j < 4; ++j) {
                    int o = (2 * w + mt2) * 16 + q * 4 + j;
                    sp[(size_t)o * 4096 + nt * 16 + i16] = a2[mt2][nt][j];
                }
    }
    __syncthreads();
}

// u: n = u&3, t0 = ai + (u>>2)*64
__device__ __forceinline__ void body_layer(
    int u, int tid, int dil, int ai, int do_res,
    const bf16_t* __restrict__ l_in, bf16_t* __restrict__ l_out,
    float* __restrict__ sbuf,
    const bf16_t* __restrict__ Ad, const bf16_t* __restrict__ Ar,
    const bf16_t* __restrict__ Ak, const float* __restrict__ cond, char* smem)
{
    bf16_t* sm0 = (bf16_t*)smem;              // l_cur
    bf16_t* sm1 = (bf16_t*)(smem + 17408);    // l_del -> bf16 sum
    bf16_t* sm2 = (bf16_t*)(smem + 34816);    // gate
    int n = u & 3, t0 = ai + (u >> 2) * 64;
    int lane = tid & 63, w = tid >> 6, i16 = lane & 15, q = lane >> 4;
    f32x4 z = {0.f,0.f,0.f,0.f};

    {
        int r = tid >> 4, col = (tid & 15) * 8;
        size_t base = (size_t)n * 8192;
        #pragma unroll
        for (int p = 0; p < 2; ++p) {
            int rr = r + p * 32;
            *(i32x4*)(sm0 + rr * PL + col) =
                *(const i32x4*)(l_in + (base + t0 + rr) * 128 + col);
            int gp = t0 - dil + rr;
            i32x4 v = {0, 0, 0, 0};
            if (gp >= 0) v = *(const i32x4*)(l_in + (base + gp) * 128 + col);
            *(i32x4*)(sm1 + rr * PL + col) = v;
        }
    }
    __syncthreads();

    f32x4 accs[4] = {z,z,z,z}, acct[4] = {z,z,z,z};
    const bf16x8* AdF = (const bf16x8*)Ad;
    #pragma unroll
    for (int kb = 0; kb < 8; ++kb) {
        const bf16_t* bsrc = (kb < 4) ? sm1 : sm0;
        int koff = (kb & 3) * 32 + q * 8;
        bf16x8 bf[4];
        #pragma unroll
        for (int nt = 0; nt < 4; ++nt)
            bf[nt] = *(const bf16x8*)(bsrc + (nt * 16 + i16) * PL + koff);
        bf16x8 a_s = AdF[((size_t)w * 8 + kb) * 64 + lane];
        bf16x8 a_t = AdF[((size_t)(w + 8) * 8 + kb) * 64 + lane];
        #pragma unroll
        for (int nt = 0; nt < 4; ++nt) {
            accs[nt] = mfma16(a_s, bf[nt], accs[nt]);
            acct[nt] = mfma16(a_t, bf[nt], acct[nt]);
        }
    }

    {
        int c_base = w * 16 + q * 4;
        float cv_s[4], cv_t[4];
        #pragma unroll
        for (int j = 0; j < 4; ++j) {
            cv_s[j] = cond[(c_base + j) * 16 + i16];
            cv_t[j] = cond[(c_base + j + 128) * 16 + i16];
        }
        #pragma unroll
        for (int nt = 0; nt < 4; ++nt) {
            bf16x4 g4;
            #pragma unroll
            for (int j = 0; j < 4; ++j) {
                float vlo = accs[nt][j] + cv_s[j];
                float vhi = acct[nt][j] + cv_t[j];
                float sg = 1.0f / (1.0f + __expf(-vlo));
                float th = 1.0f - 2.0f / (1.0f + __expf(2.0f * vhi));
                g4[j] = (bf16_t)(sg * th);
            }
            *(bf16x4*)(sm2 + (nt * 16 + i16) * PL + c_base) = g4;
        }
    }
    __syncthreads();

    int do_skip = (t0 >= 4096);
    f32x4 acc2[4] = {z,z,z,z};
    f32x4 acc3[2][4] = {{z,z,z,z},{z,z,z,z}};
    const bf16x8* ArF = (const bf16x8*)Ar;
    const bf16x8* AkF = (const bf16x8*)Ak;
    #pragma unroll
    for (int kb = 0; kb < 4; ++kb) {
        int koff = kb * 32 + q * 8;
        bf16x8 bf[4];
        #pragma unroll
        for (int nt = 0; nt < 4; ++nt)
            bf[nt] = *(const bf16x8*)(sm2 + (nt * 16 + i16) * PL + koff);
        if (do_res) {
            bf16x8 ar = ArF[((size_t)w * 4 + kb) * 64 + lane];
            #pragma unroll
            for (int nt = 0; nt < 4; ++nt) acc2[nt] = mfma16(ar, bf[nt], acc2[nt]);
        }
        if (do_skip) {
            #pragma unroll
            for (int mt2 = 0; mt2 < 2; ++mt2) {
                bf16x8 ak = AkF[((size_t)(2 * w + mt2) * 4 + kb) * 64 + lane];
                #pragma unroll
                for (int nt = 0; nt < 4; ++nt)
                    acc3[mt2][nt] = mfma16(ak, bf[nt], acc3[mt2][nt]);
            }
        }
    }

    if (do_skip) {
        float* sp = sbuf + (size_t)n * 256 * 4096 + (t0 - 4096);
        #pragma unroll
        for (int mt2 = 0; mt2 < 2; ++mt2)
            #pragma unroll
            for (int nt = 0; nt < 4; ++nt)
                #pragma unroll
                for (int j = 0; j < 4; ++j) {
                    int o = (2 * w + mt2) * 16 + q * 4 + j;
                    sp[(size_t)o * 4096 + nt * 16 + i16] += acc3[mt2][nt][j];
                }
    }

    if (do_res) {
        int c_base = w * 16 + q * 4;
        #pragma unroll
        for (int nt = 0; nt < 4; ++nt) {
            int trow = (nt * 16 + i16) * PL;
            bf16x4 lv = *(const bf16x4*)(sm0 + trow + c_base);
            bf16x4 o4;
            #pragma unroll
            for (int j = 0; j < 4; ++j)
                o4[j] = (bf16_t)((float)lv[j] + acc2[nt][j]);
            *(bf16x4*)(sm1 + trow + c_base) = o4;
        }
        __syncthreads();
        int t = tid >> 3, c0 = (tid & 7) * 16;
        bf16_t* dst = l_out + ((size_t)n * 8192 + t0 + t) * 128 + c0;
        *(i32x4*)dst = *(const i32x4*)(sm1 + t * PL + c0);
        *(i32x4*)(dst + 8) = *(const i32x4*)(sm1 + t * PL + c0 + 8);
    }
    __syncthreads();
}

// u in [0,256): n = u>>6, t0 = (u&63)*64
__device__ __forceinline__ void body_end(
    int u, int tid, const float* __restrict__ sbuf, float* __restrict__ out,
    const bf16_t* __restrict__ Ae, const float* __restrict__ cond2,
    const float* __restrict__ e1b, char* smem)
{
    bf16_t* st = (bf16_t*)smem;                    // stride PX
    float* c2 = (float*)(smem + 34816);            // 16384 B
    float* b1s = (float*)(smem + 34816 + 16384);   // 1024 B
    int n = u >> 6, t0 = (u & 63) * 64;
    int lane = tid & 63, w = tid >> 6, i16 = lane & 15, q = lane >> 4;
    f32x4 z = {0.f,0.f,0.f,0.f};
    {
        int t = tid & 63;
        for (int c = tid >> 6; c < 256; c += 8) {
            float v = sbuf[((size_t)n * 256 + c) * 4096 + t0 + t];
            st[t * PX + c] = (bf16_t)fmaxf(v, 0.f);
        }
        const f32x4* cc = (const f32x4*)(cond2 + (size_t)n * 4096);
        for (int idx = tid; idx < 1024; idx += 512) ((f32x4*)c2)[idx] = cc[idx];
        if (tid < 64) ((f32x4*)b1s)[tid] = ((const f32x4*)e1b)[tid];
    }
    __syncthreads();
    f32x4 acc[2][4] = {{z,z,z,z},{z,z,z,z}};
    #pragma unroll
    for (int kb = 0; kb < 8; ++kb) {
        int koff = kb * 32 + q * 8;
        bf16x8 bf[4];
        #pragma unroll
        for (int nt = 0; nt < 4; ++nt)
            bf[nt] = *(const bf16x8*)(st + (nt * 16 + i16) * PX + koff);
        #pragma unroll
        for (int mt2 = 0; mt2 < 2; ++mt2) {
            bf16x8 af = *(const bf16x8*)(Ae + ((((size_t)2 * w + mt2) * 8 + kb) * 64 + lane) * 8);
            #pragma unroll
            for (int nt = 0; nt < 4; ++nt) acc[mt2][nt] = mfma16(af, bf[nt], acc[mt2][nt]);
        }
    }
    #pragma unroll
    for (int mt2 = 0; mt2 < 2; ++mt2)
        #pragma unroll
        for (int j = 0; j < 4; ++j) {
            int o = (2 * w + mt2) * 16 + q * 4 + j;
            float bb = b1s[o] + c2[o * 16 + i16];
            #pragma unroll
            for (int nt = 0; nt < 4; ++nt) {
                float v = acc[mt2][nt][j] + bb;
                out[((size_t)n * 256 + o) * 4096 + t0 + nt * 16 + i16] = fmaxf(v, 0.f);
            }
        }
    __syncthreads();
}

// ================= persistent cooperative kernel =================
__global__ __launch_bounds__(512, 4) void wavenet_persistent(
    const float* __restrict__ x, bf16_t* __restrict__ la, bf16_t* __restrict__ lb,
    float* __restrict__ sbuf,
    const bf16_t* __restrict__ A1, const bf16_t* __restrict__ A2,
    const bf16_t* __restrict__ Adil, const bf16_t* __restrict__ Ares,
    const bf16_t* __restrict__ Askp, const bf16_t* __restrict__ Ae,
    const float* __restrict__ condA, const float* __restrict__ cond2,
    const float* __restrict__ e1b, const int* __restrict__ a_tab,
    float* __restrict__ out)
{
    __shared__ __align__(16) char smem[SMB];
    cg::grid_group grid = cg::this_grid();
    int nb = gridDim.x, bid = blockIdx.x, tid = threadIdx.x;

    for (int u = bid; u < 508; u += nb)
        body_start(u, tid, x, la, sbuf, A1, A2, smem);
    grid.sync();

    bf16_t* srcL = la;
    bf16_t* dstL = lb;
    #pragma unroll 1
    for (int i = 0; i < 30; ++i) {
        int dil = 1 << (i % 10);
        int ai = a_tab[i];
        int work = ((8192 - ai) >> 6) << 2;
        const float* cond = condA + (size_t)i * 16384;
        #pragma unroll 1
        for (int u = bid; u < work; u += nb)
            body_layer(u, tid, dil, ai, i < 29 ? 1 : 0, srcL, dstL, sbuf,
                       Adil + (size_t)i * 65536, Ares + (size_t)i * 16384,
                       Askp + (size_t)i * 32768, cond + (size_t)(u & 3) * 4096, smem);
        grid.sync();
        bf16_t* tmp = srcL; srcL = dstL; dstL = tmp;
    }

    for (int u = bid; u < 256; u += nb)
        body_end(u, tid, sbuf, out, Ae, cond2, e1b, smem);
}

// ================= fallback wrappers (round-4 path) =================
__global__ __launch_bounds__(512, 4) void k_start(
    const float* __restrict__ x, bf16_t* __restrict__ la, float* __restrict__ sbuf,
    const bf16_t* __restrict__ A1, const bf16_t* __restrict__ A2)
{
    __shared__ __align__(16) char smem[SMB];
    body_start(blockIdx.x * 4 + blockIdx.y, threadIdx.x, x, la, sbuf, A1, A2, smem);
}

__global__ __launch_bounds__(512, 4) void k_layer(
    const bf16_t* __restrict__ l_in, bf16_t* __restrict__ l_out,
    float* __restrict__ sbuf,
    const bf16_t* __restrict__ Ad, const bf16_t* __restrict__ Ar,
    const bf16_t* __restrict__ Ak, const float* __restrict__ cond,
    int dil, int ai, int do_res)
{
    __shared__ __align__(16) char smem[SMB];
    int u = blockIdx.x * 4 + blockIdx.y;
    body_layer(u, threadIdx.x, dil, ai, do_res, l_in, l_out, sbuf, Ad, Ar, Ak,
               cond + (size_t)(u & 3) * 4096, smem);
}

__global__ __launch_bounds__(512, 4) void k_end(
    const float* __restrict__ sbuf, float* __restrict__ out,
    const bf16_t* __restrict__ Ae, const float* __restrict__ cond2,
    const float* __restrict__ e1b)
{
    __shared__ __align__(16) char smem[SMB];
    body_end(blockIdx.y * 64 + blockIdx.x, threadIdx.x, sbuf, out, Ae, cond2, e1b, smem);
}

extern "C" void kernel_launch(void* const* d_in, const int* in_sizes, int n_in,
                              void* d_out, int out_size, void* d_ws, size_t ws_size,
                              hipStream_t stream) {
    const float* x   = (const float*)d_in[0];
    const float* en  = (const float*)d_in[1];
    const float* s1w = (const float*)d_in[2];
    const float* s2w = (const float*)d_in[3];
    const float* cw  = (const float*)d_in[4];
    const float* dw  = (const float*)d_in[5];
    const float* rw  = (const float*)d_in[6];
    const float* kw  = (const float*)d_in[7];
    const float* e1w = (const float*)d_in[8];
    const float* e1b = (const float*)d_in[9];
    const float* e2w = (const float*)d_in[10];
    const float* e2b = (const float*)d_in[11];
    float* out = (float*)d_out;

    char* p = (char*)d_ws;
    auto take = [&](size_t bytes) {
        char* r = p;
        p += (bytes + 255) & ~(size_t)255;
        return r;
    };
    bf16_t* A1   = (bf16_t*)take((size_t)128 * 256 * 2);
    bf16_t* A2   = (bf16_t*)take((size_t)256 * 128 * 2);
    bf16_t* Ae   = (bf16_t*)take((size_t)256 * 256 * 2);
    bf16_t* Adil = (bf16_t*)take((size_t)30 * 65536 * 2);
    bf16_t* Ares = (bf16_t*)take((size_t)30 * 16384 * 2);
    bf16_t* Askp = (bf16_t*)take((size_t)30 * 32768 * 2);
    float*  condA= (float*)take((size_t)30 * 16384 * 4);
    float*  cond2= (float*)take((size_t)16384 * 4);
    bf16_t* la   = (bf16_t*)take((size_t)4 * 8192 * 128 * 2);
    bf16_t* lb   = (bf16_t*)take((size_t)4 * 8192 * 128 * 2);
    float*  sbuf = (float*)take((size_t)4 * 256 * 4096 * 4);
    int*    a_tab= (int*)take(32 * 4);

    conv_batch<<<30 * 16384 / 256, 256, 0, stream>>>(rw, Ares, 128, 128, 30);
    conv_batch<<<30 * 32768 / 256, 256, 0, stream>>>(kw, Askp, 256, 128, 30);
    conv_batch<<<128 * 256 / 256, 256, 0, stream>>>(s1w, A1, 128, 256, 1);
    conv_batch<<<256 * 128 / 256, 256, 0, stream>>>(s2w, A2, 256, 128, 1);
    conv_batch<<<256 * 256 / 256, 256, 0, stream>>>(e1w, Ae, 256, 256, 1);
    conv_dil<<<30 * 65536 / 256, 256, 0, stream>>>(dw, Adil);
    cond_kernel<<<124, 256, 0, stream>>>(cw, e2w, e2b, en, condA, cond2);
    setup_a<<<1, 64, 0, stream>>>(a_tab);

    // host-side copy of the causal trim table (for fallback grid sizing)
    int a[30];
    a[29] = 4096;
    for (int i = 28; i >= 0; --i) {
        int nx = a[i + 1] - (1 << ((i + 1) % 10));
        a[i] = nx < 4096 ? (nx & ~63) : 4096;
    }

    // primary: cooperative persistent kernel, grid sized from occupancy query
    int bpc = 0;
    hipError_t qe = hipOccupancyMaxActiveBlocksPerMultiprocessor(
        &bpc, reinterpret_cast<const void*>(wavenet_persistent), 512, 0);
    hipError_t le = hipErrorUnknown;
    if (qe == hipSuccess && bpc > 0) {
        int grid = bpc * 256;
        if (grid > 508) grid = 508;
        void* kargs[] = {
            (void*)&x, (void*)&la, (void*)&lb, (void*)&sbuf,
            (void*)&A1, (void*)&A2, (void*)&Adil, (void*)&Ares, (void*)&Askp,
            (void*)&Ae, (void*)&condA, (void*)&cond2, (void*)&e1b, (void*)&a_tab,
            (void*)&out
        };
        le = hipLaunchCooperativeKernel(
            reinterpret_cast<const void*>(wavenet_persistent),
            dim3(grid), dim3(512), kargs, 0, stream);
    }

    if (le != hipSuccess) {
        // fallback: known-good round-4 sequence
        k_start<<<dim3(127, 4), 512, 0, stream>>>(x, la, sbuf, A1, A2);
        bf16_t* src = la;
        bf16_t* dst = lb;
        for (int i = 0; i < 30; ++i) {
            int ntiles = (8192 - a[i]) / 64;
            k_layer<<<dim3(ntiles, 4), 512, 0, stream>>>(src, dst, sbuf,
                Adil + (size_t)i * 65536, Ares + (size_t)i * 16384,
                Askp + (size_t)i * 32768, condA + (size_t)i * 16384,
                1 << (i % 10), a[i], i < 29 ? 1 : 0);
            bf16_t* t = src; src = dst; dst = t;
        }
        k_end<<<dim3(64, 4), 512, 0, stream>>>(sbuf, out, Ae, cond2, e1b);
    }
}

// Round 7
// 766.385 us; speedup vs baseline: 3.2649x; 3.2649x over previous
//
#include <hip/hip_runtime.h>

typedef __bf16 bf16_t;
typedef __bf16 bf16x8 __attribute__((ext_vector_type(8)));
typedef __bf16 bf16x4 __attribute__((ext_vector_type(4)));
typedef float  f32x4  __attribute__((ext_vector_type(4)));
typedef int    i32x4  __attribute__((ext_vector_type(4)));

#define PL 136   // padded row stride (elems) for [t][128] bf16 tiles
#define PX 264   // padded row stride (elems) for [t][256] bf16 tiles

__device__ __forceinline__ f32x4 mfma16(bf16x8 a, bf16x8 b, f32x4 c) {
    return __builtin_amdgcn_mfma_f32_16x16x32_bf16(a, b, c, 0, 0, 0);
}

// ---------------- merged weight conversion ----------------
__device__ __forceinline__ void conv_elem(const float* __restrict__ src,
                                          bf16_t* __restrict__ dst,
                                          int idx, int M, int K) {
    int MK = M * K;
    int lay = idx / MK;
    int r = idx - lay * MK;
    int j = r & 7, lane = (r >> 3) & 63, rest = r >> 9;
    int KB = K >> 5;
    int kb = rest % KB, mt = rest / KB;
    int m = mt * 16 + (lane & 15);
    int k = kb * 32 + ((lane >> 4) << 3) + j;
    dst[idx] = (bf16_t)src[(size_t)lay * MK + m * K + k];
}

__global__ void conv_all(const float* __restrict__ rw, const float* __restrict__ kw,
                         const float* __restrict__ s1w, const float* __restrict__ s2w,
                         const float* __restrict__ e1w, const float* __restrict__ dwt,
                         bf16_t* __restrict__ Ares, bf16_t* __restrict__ Askp,
                         bf16_t* __restrict__ A1, bf16_t* __restrict__ A2,
                         bf16_t* __restrict__ Ae, bf16_t* __restrict__ Adil) {
    int idx = blockIdx.x * 256 + threadIdx.x;
    if (idx < 491520) { conv_elem(rw, Ares, idx, 128, 128); return; }
    idx -= 491520;
    if (idx < 983040) { conv_elem(kw, Askp, idx, 256, 128); return; }
    idx -= 983040;
    if (idx < 32768) { conv_elem(s1w, A1, idx, 128, 256); return; }
    idx -= 32768;
    if (idx < 32768) { conv_elem(s2w, A2, idx, 256, 128); return; }
    idx -= 32768;
    if (idx < 65536) { conv_elem(e1w, Ae, idx, 256, 256); return; }
    idx -= 65536;
    if (idx < 1966080) {   // dil_w -> per-layer A[256][256]
        int lay = idx >> 16, r = idx & 65535;
        int j = r & 7, lane = (r >> 3) & 63, rest = r >> 9;
        int kb = rest & 7, mt = rest >> 3;
        int m = mt * 16 + (lane & 15);
        int k = kb * 32 + ((lane >> 4) << 3) + j;
        float v = (k < 128) ? dwt[(((size_t)lay * 256 + m) * 128 + k) * 2]
                            : dwt[(((size_t)lay * 256 + m) * 128 + (k - 128)) * 2 + 1];
        Adil[(size_t)lay * 65536 + r] = (bf16_t)v;
    }
}

// ---------------- conditioning precompute ----------------
__global__ void cond_kernel(const float* __restrict__ cond_w,
                            const float* __restrict__ end2_w,
                            const float* __restrict__ end2_b,
                            const float* __restrict__ en,
                            float* __restrict__ cond_all,
                            float* __restrict__ cond2) {
    __shared__ f32x4 en_s[1024];
    int bi = blockIdx.x;
    int i = bi >> 2, n = bi & 3, o = threadIdx.x;
    const f32x4* ep = (const f32x4*)(en + (size_t)n * 4096);
    for (int idx = threadIdx.x; idx < 1024; idx += 256) en_s[idx] = ep[idx];
    __syncthreads();
    const float* W = (i < 30) ? cond_w + ((size_t)i * 256 + o) * 256
                              : end2_w + (size_t)o * 256;
    f32x4 a0 = {0.f,0.f,0.f,0.f}, a1 = a0, a2 = a0, a3 = a0;
    for (int c = 0; c < 256; c += 4) {
        f32x4 wv = *(const f32x4*)(W + c);
        #pragma unroll
        for (int cc = 0; cc < 4; ++cc) {
            float wf = wv[cc];
            a0 += wf * en_s[(c + cc) * 4 + 0];
            a1 += wf * en_s[(c + cc) * 4 + 1];
            a2 += wf * en_s[(c + cc) * 4 + 2];
            a3 += wf * en_s[(c + cc) * 4 + 3];
        }
    }
    float bias = (i < 30) ? 0.f : end2_b[o];
    float* dst = (i < 30) ? cond_all + (((size_t)i * 4 + n) * 256 + o) * 16
                          : cond2 + ((size_t)n * 256 + o) * 16;
    f32x4* d4 = (f32x4*)dst;
    d4[0] = a0 + bias; d4[1] = a1 + bias; d4[2] = a2 + bias; d4[3] = a3 + bias;
}

// ---------------- start: l0 = start1@x ; s0 = start2@l0 (t>=4096) ----------------
__global__ __launch_bounds__(512, 4) void k_start(
    const float* __restrict__ x, bf16_t* __restrict__ la, float* __restrict__ sbuf,
    const bf16_t* __restrict__ A1, const bf16_t* __restrict__ A2, int t_base)
{
    __shared__ __align__(16) bf16_t xt[64 * PX];
    __shared__ __align__(16) bf16_t l0[64 * PL];
    int tid = threadIdx.x;
    int n = blockIdx.y, t0 = t_base + blockIdx.x * 64;
    int lane = tid & 63, w = tid >> 6, i16 = lane & 15, q = lane >> 4;
    f32x4 z = {0.f,0.f,0.f,0.f};
    {
        int t = tid & 63;
        for (int c = tid >> 6; c < 256; c += 8)
            xt[t * PX + c] = (bf16_t)x[((size_t)n * 256 + c) * 8192 + t0 + t];
    }
    __syncthreads();
    f32x4 acc[4] = {z,z,z,z};
    #pragma unroll
    for (int kb = 0; kb < 8; ++kb) {
        int koff = kb * 32 + q * 8;
        bf16x8 bf[4];
        #pragma unroll
        for (int nt = 0; nt < 4; ++nt)
            bf[nt] = *(const bf16x8*)(xt + (nt * 16 + i16) * PX + koff);
        bf16x8 af = *(const bf16x8*)(A1 + (((size_t)w * 8 + kb) * 64 + lane) * 8);
        #pragma unroll
        for (int nt = 0; nt < 4; ++nt) acc[nt] = mfma16(af, bf[nt], acc[nt]);
    }
    #pragma unroll
    for (int nt = 0; nt < 4; ++nt)
        #pragma unroll
        for (int j = 0; j < 4; ++j)
            l0[(nt * 16 + i16) * PL + w * 16 + q * 4 + j] = (bf16_t)acc[nt][j];
    __syncthreads();
    {
        int r = tid >> 4, col = (tid & 15) * 8;
        #pragma unroll
        for (int p = 0; p < 2; ++p) {
            int rr = r + p * 32;
            *(i32x4*)(la + ((size_t)n * 8192 + t0 + rr) * 128 + col) =
                *(const i32x4*)(l0 + rr * PL + col);
        }
    }
    if (t0 >= 4096) {
        f32x4 a2[2][4] = {{z,z,z,z},{z,z,z,z}};
        #pragma unroll
        for (int kb = 0; kb < 4; ++kb) {
            int koff = kb * 32 + q * 8;
            bf16x8 bf[4];
            #pragma unroll
            for (int nt = 0; nt < 4; ++nt)
                bf[nt] = *(const bf16x8*)(l0 + (nt * 16 + i16) * PL + koff);
            #pragma unroll
            for (int mt2 = 0; mt2 < 2; ++mt2) {
                bf16x8 af = *(const bf16x8*)(A2 + ((((size_t)2 * w + mt2) * 4 + kb) * 64 + lane) * 8);
                #pragma unroll
                for (int nt = 0; nt < 4; ++nt) a2[mt2][nt] = mfma16(af, bf[nt], a2[mt2][nt]);
            }
        }
        float* sp = sbuf + (size_t)n * 256 * 4096 + (t0 - 4096);
        #pragma unroll
        for (int mt2 = 0; mt2 < 2; ++mt2)
            #pragma unroll
            for (int nt = 0; nt < 4; ++nt)
                #pragma unroll
                for (int j = 0; j < 4; ++j) {
                    int o = (2 * w + mt2) * 16 + q * 4 + j;
                    sp[(size_t)o * 4096 + nt * 16 + i16] = a2[mt2][nt][j];
                }
    }
}

// ---------------- single layer (dil 128/256/512) — proven r4 body ----------------
__global__ __launch_bounds__(512, 4) void k_layer(
    const bf16_t* __restrict__ l_in, bf16_t* __restrict__ l_out,
    float* __restrict__ sbuf,
    const bf16_t* __restrict__ Ad, const bf16_t* __restrict__ Ar,
    const bf16_t* __restrict__ Ak, const float* __restrict__ condL,
    int dil, int t_base, int do_res)
{
    __shared__ __align__(16) bf16_t sm0[64 * PL];
    __shared__ __align__(16) bf16_t sm1[64 * PL];
    __shared__ __align__(16) bf16_t sm2[64 * PL];
    int tid = threadIdx.x;
    int n = blockIdx.y, t0 = t_base + blockIdx.x * 64;
    int lane = tid & 63, w = tid >> 6, i16 = lane & 15, q = lane >> 4;
    f32x4 z = {0.f,0.f,0.f,0.f};
    const float* cond = condL + (size_t)n * 4096;
    {
        int r = tid >> 4, col = (tid & 15) * 8;
        size_t base = (size_t)n * 8192;
        #pragma unroll
        for (int p = 0; p < 2; ++p) {
            int rr = r + p * 32;
            *(i32x4*)(sm0 + rr * PL + col) =
                *(const i32x4*)(l_in + (base + t0 + rr) * 128 + col);
            int gp = t0 - dil + rr;
            i32x4 v = {0, 0, 0, 0};
            if (gp >= 0) v = *(const i32x4*)(l_in + (base + gp) * 128 + col);
            *(i32x4*)(sm1 + rr * PL + col) = v;
        }
    }
    __syncthreads();

    f32x4 accs[4] = {z,z,z,z}, acct[4] = {z,z,z,z};
    const bf16x8* AdF = (const bf16x8*)Ad;
    #pragma unroll
    for (int kb = 0; kb < 8; ++kb) {
        const bf16_t* bsrc = (kb < 4) ? sm1 : sm0;
        int koff = (kb & 3) * 32 + q * 8;
        bf16x8 bf[4];
        #pragma unroll
        for (int nt = 0; nt < 4; ++nt)
            bf[nt] = *(const bf16x8*)(bsrc + (nt * 16 + i16) * PL + koff);
        bf16x8 a_s = AdF[((size_t)w * 8 + kb) * 64 + lane];
        bf16x8 a_t = AdF[((size_t)(w + 8) * 8 + kb) * 64 + lane];
        #pragma unroll
        for (int nt = 0; nt < 4; ++nt) {
            accs[nt] = mfma16(a_s, bf[nt], accs[nt]);
            acct[nt] = mfma16(a_t, bf[nt], acct[nt]);
        }
    }
    {
        int c_base = w * 16 + q * 4;
        float cv_s[4], cv_t[4];
        #pragma unroll
        for (int j = 0; j < 4; ++j) {
            cv_s[j] = cond[(c_base + j) * 16 + i16];
            cv_t[j] = cond[(c_base + j + 128) * 16 + i16];
        }
        #pragma unroll
        for (int nt = 0; nt < 4; ++nt) {
            bf16x4 g4;
            #pragma unroll
            for (int j = 0; j < 4; ++j) {
                float vlo = accs[nt][j] + cv_s[j];
                float vhi = acct[nt][j] + cv_t[j];
                float sg = 1.0f / (1.0f + __expf(-vlo));
                float th = 1.0f - 2.0f / (1.0f + __expf(2.0f * vhi));
                g4[j] = (bf16_t)(sg * th);
            }
            *(bf16x4*)(sm2 + (nt * 16 + i16) * PL + c_base) = g4;
        }
    }
    __syncthreads();

    int do_skip = (t0 >= 4096);
    f32x4 acc2[4] = {z,z,z,z};
    f32x4 acc3[2][4] = {{z,z,z,z},{z,z,z,z}};
    const bf16x8* ArF = (const bf16x8*)Ar;
    const bf16x8* AkF = (const bf16x8*)Ak;
    #pragma unroll
    for (int kb = 0; kb < 4; ++kb) {
        int koff = kb * 32 + q * 8;
        bf16x8 bf[4];
        #pragma unroll
        for (int nt = 0; nt < 4; ++nt)
            bf[nt] = *(const bf16x8*)(sm2 + (nt * 16 + i16) * PL + koff);
        if (do_res) {
            bf16x8 ar = ArF[((size_t)w * 4 + kb) * 64 + lane];
            #pragma unroll
            for (int nt = 0; nt < 4; ++nt) acc2[nt] = mfma16(ar, bf[nt], acc2[nt]);
        }
        if (do_skip) {
            #pragma unroll
            for (int mt2 = 0; mt2 < 2; ++mt2) {
                bf16x8 ak = AkF[((size_t)(2 * w + mt2) * 4 + kb) * 64 + lane];
                #pragma unroll
                for (int nt = 0; nt < 4; ++nt)
                    acc3[mt2][nt] = mfma16(ak, bf[nt], acc3[mt2][nt]);
            }
        }
    }
    if (do_skip) {
        float* sp = sbuf + (size_t)n * 256 * 4096 + (t0 - 4096);
        #pragma unroll
        for (int mt2 = 0; mt2 < 2; ++mt2)
            #pragma unroll
            for (int nt = 0; nt < 4; ++nt)
                #pragma unroll
                for (int j = 0; j < 4; ++j) {
                    int o = (2 * w + mt2) * 16 + q * 4 + j;
                    sp[(size_t)o * 4096 + nt * 16 + i16] += acc3[mt2][nt][j];
                }
    }
    if (do_res) {
        int c_base = w * 16 + q * 4;
        #pragma unroll
        for (int nt = 0; nt < 4; ++nt) {
            int trow = (nt * 16 + i16) * PL;
            bf16x4 lv = *(const bf16x4*)(sm0 + trow + c_base);
            bf16x4 o4;
            #pragma unroll
            for (int j = 0; j < 4; ++j)
                o4[j] = (bf16_t)((float)lv[j] + acc2[nt][j]);
            *(bf16x4*)(sm1 + trow + c_base) = o4;
        }
        __syncthreads();
        int t = tid >> 3, c0 = (tid & 7) * 16;
        bf16_t* dst = l_out + ((size_t)n * 8192 + t0 + t) * 128 + c0;
        *(i32x4*)dst = *(const i32x4*)(sm1 + t * PL + c0);
        *(i32x4*)(dst + 8) = *(const i32x4*)(sm1 + t * PL + c0 + 8);
    }
}

// ---------------- fused small-dil layers: in-LDS chain with halo recompute -------
// Block computes rows [t0-H, t0+64) of layer i0 input; applies KL layers in LDS;
// writes rows [t0, t0+64) of layer i0+KL-1 output; skip accumulated in regs.
template<int H, int KL, int D0, int D1, int D2, int D3, int D4>
__global__ __launch_bounds__(512, 4) void k_fused(
    const bf16_t* __restrict__ l_in, bf16_t* __restrict__ l_out,
    float* __restrict__ sbuf,
    const bf16_t* __restrict__ Adil_g, const bf16_t* __restrict__ Ares_g,
    const bf16_t* __restrict__ Askp_g, const float* __restrict__ condA_g,
    int i0, int t_base)
{
    constexpr int R = H + 64;
    constexpr int NT = R / 16;
    __shared__ __align__(16) bf16_t Abuf[R * PL];
    __shared__ __align__(16) bf16_t Bbuf[R * PL];
    const int dils[5] = {D0, D1, D2, D3, D4};

    int tid = threadIdx.x;
    int n = blockIdx.y, t0 = t_base + blockIdx.x * 64;
    int lane = tid & 63, w = tid >> 6, i16 = lane & 15, q = lane >> 4;
    f32x4 z = {0.f,0.f,0.f,0.f};
    int c_base = w * 16 + q * 4;

    // stage rows [t0-H, t0+64)
    for (int idx = tid; idx < R * 16; idx += 512) {
        int r = idx >> 4, col = (idx & 15) * 8;
        *(i32x4*)(Abuf + r * PL + col) =
            *(const i32x4*)(l_in + ((size_t)n * 8192 + (t0 - H) + r) * 128 + col);
    }
    __syncthreads();

    f32x4 skacc[2][4] = {{z,z,z,z},{z,z,z,z}};

    #pragma unroll 1
    for (int j = 0; j < KL; ++j) {
        int d = dils[j];
        const bf16x8* AdF = (const bf16x8*)(Adil_g + (size_t)(i0 + j) * 65536);
        const float* cn = condA_g + ((size_t)(i0 + j) * 4 + n) * 4096;
        float cv_s[4], cv_t[4];
        #pragma unroll
        for (int jj = 0; jj < 4; ++jj) {
            cv_s[jj] = cn[(c_base + jj) * 16 + i16];
            cv_t[jj] = cn[(c_base + jj + 128) * 16 + i16];
        }
        // gate phase (all ntiles; halo rows below validity produce unused garbage)
        #pragma unroll 1
        for (int nt0 = 0; nt0 < NT; nt0 += 6) {
            int CH = NT - nt0; if (CH > 6) CH = 6;
            f32x4 accs[6], acct[6];
            int rowc[6], rowd[6];
            #pragma unroll
            for (int c = 0; c < 6; ++c) {
                accs[c] = z; acct[c] = z;
                int r = (nt0 + c) * 16 + i16;
                rowc[c] = r * PL;
                int rd = r - d; if (rd < 0) rd = 0;
                rowd[c] = rd * PL;
            }
            #pragma unroll
            for (int kb = 0; kb < 8; ++kb) {
                int koff = (kb & 3) * 32 + q * 8;
                bf16x8 a_s = AdF[((size_t)w * 8 + kb) * 64 + lane];
                bf16x8 a_t = AdF[((size_t)(w + 8) * 8 + kb) * 64 + lane];
                #pragma unroll
                for (int c = 0; c < 6; ++c) {
                    if (c < CH) {
                        bf16x8 bf = *(const bf16x8*)(Abuf + (kb < 4 ? rowd[c] : rowc[c]) + koff);
                        accs[c] = mfma16(a_s, bf, accs[c]);
                        acct[c] = mfma16(a_t, bf, acct[c]);
                    }
                }
            }
            #pragma unroll
            for (int c = 0; c < 6; ++c) {
                if (c < CH) {
                    bf16x4 g4;
                    #pragma unroll
                    for (int jj = 0; jj < 4; ++jj) {
                        float vlo = accs[c][jj] + cv_s[jj];
                        float vhi = acct[c][jj] + cv_t[jj];
                        float sg = 1.0f / (1.0f + __expf(-vlo));
                        float th = 1.0f - 2.0f / (1.0f + __expf(2.0f * vhi));
                        g4[jj] = (bf16_t)(sg * th);
                    }
                    *(bf16x4*)(Bbuf + rowc[c] + c_base) = g4;
                }
            }
        }
        __syncthreads();

        // res (+ skip for output ntiles) phase
        const bf16x8* ArF = (const bf16x8*)(Ares_g + (size_t)(i0 + j) * 16384);
        const bf16x8* AkF = (const bf16x8*)(Askp_g + (size_t)(i0 + j) * 32768);
        #pragma unroll 1
        for (int nt0 = 0; nt0 < NT; nt0 += 6) {
            int CH = NT - nt0; if (CH > 6) CH = 6;
            f32x4 acc2[6];
            int rowc[6];
            #pragma unroll
            for (int c = 0; c < 6; ++c) {
                acc2[c] = z;
                rowc[c] = ((nt0 + c) * 16 + i16) * PL;
            }
            #pragma unroll
            for (int kb = 0; kb < 4; ++kb) {
                int koff = kb * 32 + q * 8;
                bf16x8 ar = ArF[((size_t)w * 4 + kb) * 64 + lane];
                bf16x8 ak0 = AkF[((size_t)(2 * w) * 4 + kb) * 64 + lane];
                bf16x8 ak1 = AkF[((size_t)(2 * w + 1) * 4 + kb) * 64 + lane];
                #pragma unroll
                for (int c = 0; c < 6; ++c) {
                    if (c < CH) {
                        bf16x8 bf = *(const bf16x8*)(Bbuf + rowc[c] + koff);
                        acc2[c] = mfma16(ar, bf, acc2[c]);
                        int ont = nt0 + c - (NT - 4);
                        if (ont >= 0) {
                            skacc[0][ont] = mfma16(ak0, bf, skacc[0][ont]);
                            skacc[1][ont] = mfma16(ak1, bf, skacc[1][ont]);
                        }
                    }
                }
            }
            #pragma unroll
            for (int c = 0; c < 6; ++c) {
                if (c < CH) {
                    bf16x4 lv = *(const bf16x4*)(Abuf + rowc[c] + c_base);
                    bf16x4 o4;
                    #pragma unroll
                    for (int jj = 0; jj < 4; ++jj)
                        o4[jj] = (bf16_t)((float)lv[jj] + acc2[c][jj]);
                    *(bf16x4*)(Abuf + rowc[c] + c_base) = o4;
                }
            }
        }
        __syncthreads();
    }

    // write output rows [H, H+64) -> l_out
    {
        int t = tid >> 3, c0 = (tid & 7) * 16;
        bf16_t* dst = l_out + ((size_t)n * 8192 + t0 + t) * 128 + c0;
        *(i32x4*)dst = *(const i32x4*)(Abuf + (H + t) * PL + c0);
        *(i32x4*)(dst + 8) = *(const i32x4*)(Abuf + (H + t) * PL + c0 + 8);
    }
    // one skip RMW for all KL layers
    if (t0 >= 4096) {
        float* sp = sbuf + (size_t)n * 256 * 4096 + (t0 - 4096);
        #pragma unroll
        for (int mt2 = 0; mt2 < 2; ++mt2)
            #pragma unroll
            for (int ont = 0; ont < 4; ++ont)
                #pragma unroll
                for (int jj = 0; jj < 4; ++jj) {
                    int o = (2 * w + mt2) * 16 + q * 4 + jj;
                    sp[(size_t)o * 4096 + ont * 16 + i16] += skacc[mt2][ont][jj];
                }
    }
}

// ---------------- end: out = relu(end1@relu(s) + b1 + cond2_tiled) ----------------
__global__ __launch_bounds__(512) void k_end(
    const float* __restrict__ sbuf, float* __restrict__ out,
    const bf16_t* __restrict__ Ae, const float* __restrict__ cond2,
    const float* __restrict__ b1)
{
    __shared__ __align__(16) bf16_t st[64 * PX];
    __shared__ float c2[4096];
    __shared__ float b1s[256];
    int tid = threadIdx.x;
    int n = blockIdx.y, t0 = blockIdx.x * 64;
    int lane = tid & 63, w = tid >> 6, i16 = lane & 15, q = lane >> 4;
    f32x4 z = {0.f,0.f,0.f,0.f};
    {
        int t = tid & 63;
        for (int c = tid >> 6; c < 256; c += 8) {
            float v = sbuf[((size_t)n * 256 + c) * 4096 + t0 + t];
            st[t * PX + c] = (bf16_t)fmaxf(v, 0.f);
        }
        const f32x4* cc = (const f32x4*)(cond2 + (size_t)n * 4096);
        for (int idx = tid; idx < 1024; idx += 512) ((f32x4*)c2)[idx] = cc[idx];
        if (tid < 64) ((f32x4*)b1s)[tid] = ((const f32x4*)b1)[tid];
    }
    __syncthreads();
    f32x4 acc[2][4] = {{z,z,z,z},{z,z,z,z}};
    #pragma unroll
    for (int kb = 0; kb < 8; ++kb) {
        int koff = kb * 32 + q * 8;
        bf16x8 bf[4];
        #pragma unroll
        for (int nt = 0; nt < 4; ++nt)
            bf[nt] = *(const bf16x8*)(st + (nt * 16 + i16) * PX + koff);
        #pragma unroll
        for (int mt2 = 0; mt2 < 2; ++mt2) {
            bf16x8 af = *(const bf16x8*)(Ae + ((((size_t)2 * w + mt2) * 8 + kb) * 64 + lane) * 8);
            #pragma unroll
            for (int nt = 0; nt < 4; ++nt) acc[mt2][nt] = mfma16(af, bf[nt], acc[mt2][nt]);
        }
    }
    #pragma unroll
    for (int mt2 = 0; mt2 < 2; ++mt2)
        #pragma unroll
        for (int j = 0; j < 4; ++j) {
            int o = (2 * w + mt2) * 16 + q * 4 + j;
            float bb = b1s[o] + c2[o * 16 + i16];
            #pragma unroll
            for (int nt = 0; nt < 4; ++nt) {
                float v = acc[mt2][nt][j] + bb;
                out[((size_t)n * 256 + o) * 4096 + t0 + nt * 16 + i16] = fmaxf(v, 0.f);
            }
        }
}

extern "C" void kernel_launch(void* const* d_in, const int* in_sizes, int n_in,
                              void* d_out, int out_size, void* d_ws, size_t ws_size,
                              hipStream_t stream) {
    const float* x   = (const float*)d_in[0];
    const float* en  = (const float*)d_in[1];
    const float* s1w = (const float*)d_in[2];
    const float* s2w = (const float*)d_in[3];
    const float* cw  = (const float*)d_in[4];
    const float* dw  = (const float*)d_in[5];
    const float* rw  = (const float*)d_in[6];
    const float* kw  = (const float*)d_in[7];
    const float* e1w = (const float*)d_in[8];
    const float* e1b = (const float*)d_in[9];
    const float* e2w = (const float*)d_in[10];
    const float* e2b = (const float*)d_in[11];
    float* out = (float*)d_out;

    char* p = (char*)d_ws;
    auto take = [&](size_t bytes) {
        char* r = p;
        p += (bytes + 255) & ~(size_t)255;
        return r;
    };
    bf16_t* A1   = (bf16_t*)take((size_t)128 * 256 * 2);
    bf16_t* A2   = (bf16_t*)take((size_t)256 * 128 * 2);
    bf16_t* Ae   = (bf16_t*)take((size_t)256 * 256 * 2);
    bf16_t* Adil = (bf16_t*)take((size_t)30 * 65536 * 2);
    bf16_t* Ares = (bf16_t*)take((size_t)30 * 16384 * 2);
    bf16_t* Askp = (bf16_t*)take((size_t)30 * 32768 * 2);
    float*  condA= (float*)take((size_t)30 * 16384 * 4);
    float*  cond2= (float*)take((size_t)16384 * 4);
    bf16_t* la   = (bf16_t*)take((size_t)4 * 8192 * 128 * 2);
    bf16_t* lb   = (bf16_t*)take((size_t)4 * 8192 * 128 * 2);
    float*  sbuf = (float*)take((size_t)4 * 256 * 4096 * 4);

    // 2 prep launches
    conv_all<<<13952, 256, 0, stream>>>(rw, kw, s1w, s2w, e1w, dw,
                                        Ares, Askp, A1, A2, Ae, Adil);
    cond_kernel<<<124, 256, 0, stream>>>(cw, e2w, e2b, en, condA, cond2);

    // per-stage causal-trim bases (backward recursion, 64-aligned)
    int baseS[3][3], baseF2[3], baseF5[3];
    int need = 4096;
    for (int dec = 2; dec >= 0; --dec) {
        for (int s = 2; s >= 0; --s) {           // dils 512,256,128
            baseS[dec][s] = need & ~63;
            need = baseS[dec][s] - (128 << s);
        }
        baseF2[dec] = need & ~63; need = baseF2[dec] - 96;   // dils 32,64
        baseF5[dec] = need & ~63; need = baseF5[dec] - 32;   // dils 1..16
    }
    int base_start = need & ~63;
    if (base_start < 64) base_start = 64;

    k_start<<<dim3((8192 - base_start) / 64, 4), 512, 0, stream>>>(
        x, la, sbuf, A1, A2, base_start);

    bf16_t* src = la;
    bf16_t* dst = lb;
    for (int dec = 0; dec < 3; ++dec) {
        int i0 = dec * 10;
        k_fused<32, 5, 1, 2, 4, 8, 16>
            <<<dim3((8192 - baseF5[dec]) / 64, 4), 512, 0, stream>>>(
                src, dst, sbuf, Adil, Ares, Askp, condA, i0, baseF5[dec]);
        { bf16_t* t = src; src = dst; dst = t; }
        k_fused<96, 2, 32, 64, 1, 1, 1>
            <<<dim3((8192 - baseF2[dec]) / 64, 4), 512, 0, stream>>>(
                src, dst, sbuf, Adil, Ares, Askp, condA, i0 + 5, baseF2[dec]);
        { bf16_t* t = src; src = dst; dst = t; }
        for (int s = 0; s < 3; ++s) {
            int li = i0 + 7 + s;
            k_layer<<<dim3((8192 - baseS[dec][s]) / 64, 4), 512, 0, stream>>>(
                src, dst, sbuf, Adil + (size_t)li * 65536,
                Ares + (size_t)li * 16384, Askp + (size_t)li * 32768,
                condA + (size_t)li * 16384, 128 << s, baseS[dec][s],
                li < 29 ? 1 : 0);
            bf16_t* t = src; src = dst; dst = t;
        }
    }
    k_end<<<dim3(64, 4), 512, 0, stream>>>(sbuf, out, Ae, cond2, e1b);
}

// Round 8
// 651.817 us; speedup vs baseline: 3.8387x; 1.1758x over previous
//
#include <hip/hip_runtime.h>

typedef __bf16 bf16_t;
typedef __bf16 bf16x8 __attribute__((ext_vector_type(8)));
typedef __bf16 bf16x4 __attribute__((ext_vector_type(4)));
typedef float  f32x4  __attribute__((ext_vector_type(4)));
typedef int    i32x4  __attribute__((ext_vector_type(4)));

#define PL 136   // padded row stride (elems) for [t][128] bf16 tiles
#define PX 264   // padded row stride (elems) for [t][256] bf16 tiles

__device__ __forceinline__ f32x4 mfma16(bf16x8 a, bf16x8 b, f32x4 c) {
    return __builtin_amdgcn_mfma_f32_16x16x32_bf16(a, b, c, 0, 0, 0);
}

// ---------------- merged weight conversion ----------------
__device__ __forceinline__ void conv_elem(const float* __restrict__ src,
                                          bf16_t* __restrict__ dst,
                                          int idx, int M, int K) {
    int MK = M * K;
    int lay = idx / MK;
    int r = idx - lay * MK;
    int j = r & 7, lane = (r >> 3) & 63, rest = r >> 9;
    int KB = K >> 5;
    int kb = rest % KB, mt = rest / KB;
    int m = mt * 16 + (lane & 15);
    int k = kb * 32 + ((lane >> 4) << 3) + j;
    dst[idx] = (bf16_t)src[(size_t)lay * MK + m * K + k];
}

__global__ void conv_all(const float* __restrict__ rw, const float* __restrict__ kw,
                         const float* __restrict__ s1w, const float* __restrict__ s2w,
                         const float* __restrict__ e1w, const float* __restrict__ dwt,
                         bf16_t* __restrict__ Ares, bf16_t* __restrict__ Askp,
                         bf16_t* __restrict__ A1, bf16_t* __restrict__ A2,
                         bf16_t* __restrict__ Ae, bf16_t* __restrict__ Adil) {
    int idx = blockIdx.x * 256 + threadIdx.x;
    if (idx < 491520) { conv_elem(rw, Ares, idx, 128, 128); return; }
    idx -= 491520;
    if (idx < 983040) { conv_elem(kw, Askp, idx, 256, 128); return; }
    idx -= 983040;
    if (idx < 32768) { conv_elem(s1w, A1, idx, 128, 256); return; }
    idx -= 32768;
    if (idx < 32768) { conv_elem(s2w, A2, idx, 256, 128); return; }
    idx -= 32768;
    if (idx < 65536) { conv_elem(e1w, Ae, idx, 256, 256); return; }
    idx -= 65536;
    if (idx < 1966080) {   // dil_w -> per-layer A[256][256]
        int lay = idx >> 16, r = idx & 65535;
        int j = r & 7, lane = (r >> 3) & 63, rest = r >> 9;
        int kb = rest & 7, mt = rest >> 3;
        int m = mt * 16 + (lane & 15);
        int k = kb * 32 + ((lane >> 4) << 3) + j;
        float v = (k < 128) ? dwt[(((size_t)lay * 256 + m) * 128 + k) * 2]
                            : dwt[(((size_t)lay * 256 + m) * 128 + (k - 128)) * 2 + 1];
        Adil[(size_t)lay * 65536 + r] = (bf16_t)v;
    }
}

// ---------------- conditioning precompute ----------------
__global__ void cond_kernel(const float* __restrict__ cond_w,
                            const float* __restrict__ end2_w,
                            const float* __restrict__ end2_b,
                            const float* __restrict__ en,
                            float* __restrict__ cond_all,
                            float* __restrict__ cond2) {
    __shared__ f32x4 en_s[1024];
    int bi = blockIdx.x;
    int i = bi >> 2, n = bi & 3, o = threadIdx.x;
    const f32x4* ep = (const f32x4*)(en + (size_t)n * 4096);
    for (int idx = threadIdx.x; idx < 1024; idx += 256) en_s[idx] = ep[idx];
    __syncthreads();
    const float* W = (i < 30) ? cond_w + ((size_t)i * 256 + o) * 256
                              : end2_w + (size_t)o * 256;
    f32x4 a0 = {0.f,0.f,0.f,0.f}, a1 = a0, a2 = a0, a3 = a0;
    for (int c = 0; c < 256; c += 4) {
        f32x4 wv = *(const f32x4*)(W + c);
        #pragma unroll
        for (int cc = 0; cc < 4; ++cc) {
            float wf = wv[cc];
            a0 += wf * en_s[(c + cc) * 4 + 0];
            a1 += wf * en_s[(c + cc) * 4 + 1];
            a2 += wf * en_s[(c + cc) * 4 + 2];
            a3 += wf * en_s[(c + cc) * 4 + 3];
        }
    }
    float bias = (i < 30) ? 0.f : end2_b[o];
    float* dst = (i < 30) ? cond_all + (((size_t)i * 4 + n) * 256 + o) * 16
                          : cond2 + ((size_t)n * 256 + o) * 16;
    f32x4* d4 = (f32x4*)dst;
    d4[0] = a0 + bias; d4[1] = a1 + bias; d4[2] = a2 + bias; d4[3] = a3 + bias;
}

// ---------------- start: l0 = start1@x ; s0 = start2@l0 (t>=4096) ----------------
__global__ __launch_bounds__(512, 4) void k_start(
    const float* __restrict__ x, bf16_t* __restrict__ la, float* __restrict__ sbuf,
    const bf16_t* __restrict__ A1, const bf16_t* __restrict__ A2, int t_base)
{
    __shared__ __align__(16) bf16_t xt[64 * PX];
    __shared__ __align__(16) bf16_t l0[64 * PL];
    int tid = threadIdx.x;
    int n = blockIdx.y, t0 = t_base + blockIdx.x * 64;
    int lane = tid & 63, w = tid >> 6, i16 = lane & 15, q = lane >> 4;
    f32x4 z = {0.f,0.f,0.f,0.f};
    {
        int t = tid & 63;
        for (int c = tid >> 6; c < 256; c += 8)
            xt[t * PX + c] = (bf16_t)x[((size_t)n * 256 + c) * 8192 + t0 + t];
    }
    __syncthreads();
    f32x4 acc[4] = {z,z,z,z};
    #pragma unroll
    for (int kb = 0; kb < 8; ++kb) {
        int koff = kb * 32 + q * 8;
        bf16x8 bf[4];
        #pragma unroll
        for (int nt = 0; nt < 4; ++nt)
            bf[nt] = *(const bf16x8*)(xt + (nt * 16 + i16) * PX + koff);
        bf16x8 af = *(const bf16x8*)(A1 + (((size_t)w * 8 + kb) * 64 + lane) * 8);
        #pragma unroll
        for (int nt = 0; nt < 4; ++nt) acc[nt] = mfma16(af, bf[nt], acc[nt]);
    }
    #pragma unroll
    for (int nt = 0; nt < 4; ++nt)
        #pragma unroll
        for (int j = 0; j < 4; ++j)
            l0[(nt * 16 + i16) * PL + w * 16 + q * 4 + j] = (bf16_t)acc[nt][j];
    __syncthreads();
    {
        int r = tid >> 4, col = (tid & 15) * 8;
        #pragma unroll
        for (int p = 0; p < 2; ++p) {
            int rr = r + p * 32;
            *(i32x4*)(la + ((size_t)n * 8192 + t0 + rr) * 128 + col) =
                *(const i32x4*)(l0 + rr * PL + col);
        }
    }
    if (t0 >= 4096) {
        f32x4 a2[2][4] = {{z,z,z,z},{z,z,z,z}};
        #pragma unroll
        for (int kb = 0; kb < 4; ++kb) {
            int koff = kb * 32 + q * 8;
            bf16x8 bf[4];
            #pragma unroll
            for (int nt = 0; nt < 4; ++nt)
                bf[nt] = *(const bf16x8*)(l0 + (nt * 16 + i16) * PL + koff);
            #pragma unroll
            for (int mt2 = 0; mt2 < 2; ++mt2) {
                bf16x8 af = *(const bf16x8*)(A2 + ((((size_t)2 * w + mt2) * 4 + kb) * 64 + lane) * 8);
                #pragma unroll
                for (int nt = 0; nt < 4; ++nt) a2[mt2][nt] = mfma16(af, bf[nt], a2[mt2][nt]);
            }
        }
        float* sp = sbuf + (size_t)n * 256 * 4096 + (t0 - 4096);
        #pragma unroll
        for (int mt2 = 0; mt2 < 2; ++mt2)
            #pragma unroll
            for (int nt = 0; nt < 4; ++nt)
                #pragma unroll
                for (int j = 0; j < 4; ++j) {
                    int o = (2 * w + mt2) * 16 + q * 4 + j;
                    sp[(size_t)o * 4096 + nt * 16 + i16] = a2[mt2][nt][j];
                }
    }
}

// ---------------- single layer: GEMM1 + gate; skip deferred via G (USEG=1) ------
// USEG=1: write bf16 gate tile to Gl (streaming), no skip GEMM / no sbuf RMW.
// USEG=0: legacy r4 path (in-layer skip GEMM + sbuf RMW) — ws-size fallback.
template<int USEG>
__global__ __launch_bounds__(512, 4) void k_layer(
    const bf16_t* __restrict__ l_in, bf16_t* __restrict__ l_out,
    float* __restrict__ sbuf, bf16_t* __restrict__ Gl,
    const bf16_t* __restrict__ Ad, const bf16_t* __restrict__ Ar,
    const bf16_t* __restrict__ Ak, const float* __restrict__ condL,
    int dil, int t_base, int do_res)
{
    __shared__ __align__(16) bf16_t sm0[64 * PL];
    __shared__ __align__(16) bf16_t sm1[64 * PL];
    __shared__ __align__(16) bf16_t sm2[64 * PL];
    int tid = threadIdx.x;
    int n = blockIdx.y, t0 = t_base + blockIdx.x * 64;
    int lane = tid & 63, w = tid >> 6, i16 = lane & 15, q = lane >> 4;
    f32x4 z = {0.f,0.f,0.f,0.f};
    const float* cond = condL + (size_t)n * 4096;
    {
        int r = tid >> 4, col = (tid & 15) * 8;
        size_t base = (size_t)n * 8192;
        #pragma unroll
        for (int p = 0; p < 2; ++p) {
            int rr = r + p * 32;
            *(i32x4*)(sm0 + rr * PL + col) =
                *(const i32x4*)(l_in + (base + t0 + rr) * 128 + col);
            int gp = t0 - dil + rr;
            i32x4 v = {0, 0, 0, 0};
            if (gp >= 0) v = *(const i32x4*)(l_in + (base + gp) * 128 + col);
            *(i32x4*)(sm1 + rr * PL + col) = v;
        }
    }
    __syncthreads();

    // GEMM1: d = [W0 W1] @ [l_del; l_cur], M=256 K=256
    f32x4 accs[4] = {z,z,z,z}, acct[4] = {z,z,z,z};
    const bf16x8* AdF = (const bf16x8*)Ad;
    #pragma unroll
    for (int kb = 0; kb < 8; ++kb) {
        const bf16_t* bsrc = (kb < 4) ? sm1 : sm0;
        int koff = (kb & 3) * 32 + q * 8;
        bf16x8 bf[4];
        #pragma unroll
        for (int nt = 0; nt < 4; ++nt)
            bf[nt] = *(const bf16x8*)(bsrc + (nt * 16 + i16) * PL + koff);
        bf16x8 a_s = AdF[((size_t)w * 8 + kb) * 64 + lane];
        bf16x8 a_t = AdF[((size_t)(w + 8) * 8 + kb) * 64 + lane];
        #pragma unroll
        for (int nt = 0; nt < 4; ++nt) {
            accs[nt] = mfma16(a_s, bf[nt], accs[nt]);
            acct[nt] = mfma16(a_t, bf[nt], acct[nt]);
        }
    }
    {   // gate in-register -> sm2
        int c_base = w * 16 + q * 4;
        float cv_s[4], cv_t[4];
        #pragma unroll
        for (int j = 0; j < 4; ++j) {
            cv_s[j] = cond[(c_base + j) * 16 + i16];
            cv_t[j] = cond[(c_base + j + 128) * 16 + i16];
        }
        #pragma unroll
        for (int nt = 0; nt < 4; ++nt) {
            bf16x4 g4;
            #pragma unroll
            for (int j = 0; j < 4; ++j) {
                float vlo = accs[nt][j] + cv_s[j];
                float vhi = acct[nt][j] + cv_t[j];
                float sg = 1.0f / (1.0f + __expf(-vlo));
                float th = 1.0f - 2.0f / (1.0f + __expf(2.0f * vhi));
                g4[j] = (bf16_t)(sg * th);
            }
            *(bf16x4*)(sm2 + (nt * 16 + i16) * PL + c_base) = g4;
        }
    }
    __syncthreads();

    if (USEG) {
        // stream gate tile to G (t >= 4096 region only) — overlaps with res GEMM
        if (t0 >= 4096) {
            int tr = tid >> 3, c0 = (tid & 7) * 16;
            bf16_t* gd = Gl + ((size_t)n * 4096 + (t0 - 4096) + tr) * 128 + c0;
            *(i32x4*)gd = *(const i32x4*)(sm2 + tr * PL + c0);
            *(i32x4*)(gd + 8) = *(const i32x4*)(sm2 + tr * PL + c0 + 8);
        }
    }

    f32x4 acc2[4] = {z,z,z,z};
    const bf16x8* ArF = (const bf16x8*)Ar;
    if (do_res || !USEG) {
        int do_skip = (!USEG) && (t0 >= 4096);
        f32x4 acc3[2][4] = {{z,z,z,z},{z,z,z,z}};
        const bf16x8* AkF = (const bf16x8*)Ak;
        #pragma unroll
        for (int kb = 0; kb < 4; ++kb) {
            int koff = kb * 32 + q * 8;
            bf16x8 bf[4];
            #pragma unroll
            for (int nt = 0; nt < 4; ++nt)
                bf[nt] = *(const bf16x8*)(sm2 + (nt * 16 + i16) * PL + koff);
            if (do_res) {
                bf16x8 ar = ArF[((size_t)w * 4 + kb) * 64 + lane];
                #pragma unroll
                for (int nt = 0; nt < 4; ++nt) acc2[nt] = mfma16(ar, bf[nt], acc2[nt]);
            }
            if (do_skip) {
                #pragma unroll
                for (int mt2 = 0; mt2 < 2; ++mt2) {
                    bf16x8 ak = AkF[((size_t)(2 * w + mt2) * 4 + kb) * 64 + lane];
                    #pragma unroll
                    for (int nt = 0; nt < 4; ++nt)
                        acc3[mt2][nt] = mfma16(ak, bf[nt], acc3[mt2][nt]);
                }
            }
        }
        if (do_skip) {
            float* sp = sbuf + (size_t)n * 256 * 4096 + (t0 - 4096);
            #pragma unroll
            for (int mt2 = 0; mt2 < 2; ++mt2)
                #pragma unroll
                for (int nt = 0; nt < 4; ++nt)
                    #pragma unroll
                    for (int j = 0; j < 4; ++j) {
                        int o = (2 * w + mt2) * 16 + q * 4 + j;
                        sp[(size_t)o * 4096 + nt * 16 + i16] += acc3[mt2][nt][j];
                    }
        }
    }

    if (do_res) {
        int c_base = w * 16 + q * 4;
        #pragma unroll
        for (int nt = 0; nt < 4; ++nt) {
            int trow = (nt * 16 + i16) * PL;
            bf16x4 lv = *(const bf16x4*)(sm0 + trow + c_base);
            bf16x4 o4;
            #pragma unroll
            for (int j = 0; j < 4; ++j)
                o4[j] = (bf16_t)((float)lv[j] + acc2[nt][j]);
            *(bf16x4*)(sm1 + trow + c_base) = o4;
        }
        __syncthreads();
        int t = tid >> 3, c0 = (tid & 7) * 16;
        bf16_t* dst = l_out + ((size_t)n * 8192 + t0 + t) * 128 + c0;
        *(i32x4*)dst = *(const i32x4*)(sm1 + t * PL + c0);
        *(i32x4*)(dst + 8) = *(const i32x4*)(sm1 + t * PL + c0 + 8);
    }
}

// ---------------- deferred skip mega-GEMM: s += sum_i skip_i @ g_i ----------------
__global__ __launch_bounds__(512) void k_skip(
    const bf16_t* __restrict__ G, float* __restrict__ sbuf,
    const bf16_t* __restrict__ Askp)
{
    __shared__ __align__(16) bf16_t gbuf[64 * PL];
    int tid = threadIdx.x;
    int n = blockIdx.y, t0 = blockIdx.x * 64;
    int lane = tid & 63, w = tid >> 6, i16 = lane & 15, q = lane >> 4;
    f32x4 z = {0.f,0.f,0.f,0.f};
    f32x4 acc[2][4] = {{z,z,z,z},{z,z,z,z}};
    int r = tid >> 3, cA = (tid & 7) * 8;
    const size_t GLS = (size_t)4 * 4096 * 128;   // per-layer stride in G
    const bf16_t* gb = G + ((size_t)n * 4096 + t0 + r) * 128 + cA;
    i32x4 v0 = *(const i32x4*)(gb);
    i32x4 v1 = *(const i32x4*)(gb + 64);
    #pragma unroll 1
    for (int i = 0; i < 30; ++i) {
        __syncthreads();
        *(i32x4*)(gbuf + r * PL + cA) = v0;
        *(i32x4*)(gbuf + r * PL + cA + 64) = v1;
        if (i + 1 < 30) {
            v0 = *(const i32x4*)(gb + (size_t)(i + 1) * GLS);
            v1 = *(const i32x4*)(gb + (size_t)(i + 1) * GLS + 64);
        }
        __syncthreads();
        const bf16x8* AkF = (const bf16x8*)(Askp + (size_t)i * 32768);
        #pragma unroll
        for (int kb = 0; kb < 4; ++kb) {
            int koff = kb * 32 + q * 8;
            bf16x8 ak0 = AkF[((size_t)(2 * w) * 4 + kb) * 64 + lane];
            bf16x8 ak1 = AkF[((size_t)(2 * w + 1) * 4 + kb) * 64 + lane];
            #pragma unroll
            for (int nt = 0; nt < 4; ++nt) {
                bf16x8 bf = *(const bf16x8*)(gbuf + (nt * 16 + i16) * PL + koff);
                acc[0][nt] = mfma16(ak0, bf, acc[0][nt]);
                acc[1][nt] = mfma16(ak1, bf, acc[1][nt]);
            }
        }
    }
    float* sp = sbuf + (size_t)n * 256 * 4096 + t0;
    #pragma unroll
    for (int mt2 = 0; mt2 < 2; ++mt2)
        #pragma unroll
        for (int nt = 0; nt < 4; ++nt)
            #pragma unroll
            for (int j = 0; j < 4; ++j) {
                int o = (2 * w + mt2) * 16 + q * 4 + j;
                sp[(size_t)o * 4096 + nt * 16 + i16] += acc[mt2][nt][j];
            }
}

// ---------------- end: out = relu(end1@relu(s) + b1 + cond2_tiled) ----------------
__global__ __launch_bounds__(512) void k_end(
    const float* __restrict__ sbuf, float* __restrict__ out,
    const bf16_t* __restrict__ Ae, const float* __restrict__ cond2,
    const float* __restrict__ b1)
{
    __shared__ __align__(16) bf16_t st[64 * PX];
    __shared__ float c2[4096];
    __shared__ float b1s[256];
    int tid = threadIdx.x;
    int n = blockIdx.y, t0 = blockIdx.x * 64;
    int lane = tid & 63, w = tid >> 6, i16 = lane & 15, q = lane >> 4;
    f32x4 z = {0.f,0.f,0.f,0.f};
    {
        int t = tid & 63;
        for (int c = tid >> 6; c < 256; c += 8) {
            float v = sbuf[((size_t)n * 256 + c) * 4096 + t0 + t];
            st[t * PX + c] = (bf16_t)fmaxf(v, 0.f);
        }
        const f32x4* cc = (const f32x4*)(cond2 + (size_t)n * 4096);
        for (int idx = tid; idx < 1024; idx += 512) ((f32x4*)c2)[idx] = cc[idx];
        if (tid < 64) ((f32x4*)b1s)[tid] = ((const f32x4*)b1)[tid];
    }
    __syncthreads();
    f32x4 acc[2][4] = {{z,z,z,z},{z,z,z,z}};
    #pragma unroll
    for (int kb = 0; kb < 8; ++kb) {
        int koff = kb * 32 + q * 8;
        bf16x8 bf[4];
        #pragma unroll
        for (int nt = 0; nt < 4; ++nt)
            bf[nt] = *(const bf16x8*)(st + (nt * 16 + i16) * PX + koff);
        #pragma unroll
        for (int mt2 = 0; mt2 < 2; ++mt2) {
            bf16x8 af = *(const bf16x8*)(Ae + ((((size_t)2 * w + mt2) * 8 + kb) * 64 + lane) * 8);
            #pragma unroll
            for (int nt = 0; nt < 4; ++nt) acc[mt2][nt] = mfma16(af, bf[nt], acc[mt2][nt]);
        }
    }
    #pragma unroll
    for (int mt2 = 0; mt2 < 2; ++mt2)
        #pragma unroll
        for (int j = 0; j < 4; ++j) {
            int o = (2 * w + mt2) * 16 + q * 4 + j;
            float bb = b1s[o] + c2[o * 16 + i16];
            #pragma unroll
            for (int nt = 0; nt < 4; ++nt) {
                float v = acc[mt2][nt][j] + bb;
                out[((size_t)n * 256 + o) * 4096 + t0 + nt * 16 + i16] = fmaxf(v, 0.f);
            }
        }
}

extern "C" void kernel_launch(void* const* d_in, const int* in_sizes, int n_in,
                              void* d_out, int out_size, void* d_ws, size_t ws_size,
                              hipStream_t stream) {
    const float* x   = (const float*)d_in[0];
    const float* en  = (const float*)d_in[1];
    const float* s1w = (const float*)d_in[2];
    const float* s2w = (const float*)d_in[3];
    const float* cw  = (const float*)d_in[4];
    const float* dw  = (const float*)d_in[5];
    const float* rw  = (const float*)d_in[6];
    const float* kw  = (const float*)d_in[7];
    const float* e1w = (const float*)d_in[8];
    const float* e1b = (const float*)d_in[9];
    const float* e2w = (const float*)d_in[10];
    const float* e2b = (const float*)d_in[11];
    float* out = (float*)d_out;

    char* p = (char*)d_ws;
    auto take = [&](size_t bytes) {
        char* r = p;
        p += (bytes + 255) & ~(size_t)255;
        return r;
    };
    bf16_t* A1   = (bf16_t*)take((size_t)128 * 256 * 2);
    bf16_t* A2   = (bf16_t*)take((size_t)256 * 128 * 2);
    bf16_t* Ae   = (bf16_t*)take((size_t)256 * 256 * 2);
    bf16_t* Adil = (bf16_t*)take((size_t)30 * 65536 * 2);
    bf16_t* Ares = (bf16_t*)take((size_t)30 * 16384 * 2);
    bf16_t* Askp = (bf16_t*)take((size_t)30 * 32768 * 2);
    float*  condA= (float*)take((size_t)30 * 16384 * 4);
    float*  cond2= (float*)take((size_t)16384 * 4);
    bf16_t* la   = (bf16_t*)take((size_t)4 * 8192 * 128 * 2);
    bf16_t* lb   = (bf16_t*)take((size_t)4 * 8192 * 128 * 2);
    float*  sbuf = (float*)take((size_t)4 * 256 * 4096 * 4);
    bf16_t* G    = (bf16_t*)take((size_t)30 * 4 * 4096 * 128 * 2);  // last
    bool useG = ((size_t)(p - (char*)d_ws) <= ws_size);

    conv_all<<<13952, 256, 0, stream>>>(rw, kw, s1w, s2w, e1w, dw,
                                        Ares, Askp, A1, A2, Ae, Adil);
    cond_kernel<<<124, 256, 0, stream>>>(cw, e2w, e2b, en, condA, cond2);

    // causal trim table (host)
    int a[30];
    a[29] = 4096;
    for (int i = 28; i >= 0; --i) {
        int nx = a[i + 1] - (1 << ((i + 1) % 10));
        a[i] = nx < 4096 ? (nx & ~63) : 4096;
    }

    k_start<<<dim3(127, 4), 512, 0, stream>>>(x, la, sbuf, A1, A2, 64);

    bf16_t* src = la;
    bf16_t* dst = lb;
    for (int i = 0; i < 30; ++i) {
        dim3 grid((8192 - a[i]) / 64, 4);
        if (useG)
            k_layer<1><<<grid, 512, 0, stream>>>(src, dst, sbuf,
                G + (size_t)i * 4 * 4096 * 128,
                Adil + (size_t)i * 65536, Ares + (size_t)i * 16384,
                Askp + (size_t)i * 32768, condA + (size_t)i * 16384,
                1 << (i % 10), a[i], i < 29 ? 1 : 0);
        else
            k_layer<0><<<grid, 512, 0, stream>>>(src, dst, sbuf, (bf16_t*)nullptr,
                Adil + (size_t)i * 65536, Ares + (size_t)i * 16384,
                Askp + (size_t)i * 32768, condA + (size_t)i * 16384,
                1 << (i % 10), a[i], i < 29 ? 1 : 0);
        bf16_t* t = src; src = dst; dst = t;
    }
    if (useG)
        k_skip<<<dim3(64, 4), 512, 0, stream>>>(G, sbuf, Askp);
    k_end<<<dim3(64, 4), 512, 0, stream>>>(sbuf, out, Ae, cond2, e1b);
}